// Round 9
// baseline (400.631 us; speedup 1.0000x reference)
//
#include <hip/hip_runtime.h>
#include <hip/hip_bf16.h>

typedef __hip_bfloat16 bf16_t;
typedef __attribute__((ext_vector_type(8))) __bf16 bf16x8;
typedef __attribute__((ext_vector_type(4))) float f32x4;
typedef __attribute__((ext_vector_type(8))) unsigned short u16x8;

// ---------------------------------------------------------------- helpers

__device__ __forceinline__ void gld_lds16(const void* g, void* l) {
    // async global->LDS, 16B per lane. LDS dest is wave-uniform base + lane*16.
    __builtin_amdgcn_global_load_lds(
        (const __attribute__((address_space(1))) unsigned int*)g,
        (__attribute__((address_space(3))) unsigned int*)l,
        16, 0, 0);
}

__device__ __forceinline__ unsigned short bf16_bits(float x) {
    bf16_t b = __float2bfloat16(x);
    return *reinterpret_cast<unsigned short*>(&b);
}

// ---------------------------------------------------------------- convert x -> bf16

__global__ __launch_bounds__(256) void cvt_f32_bf16_kernel(
    const float* __restrict__ in, bf16_t* __restrict__ out, long n4) {
    long stride = (long)gridDim.x * blockDim.x;
    for (long i = (long)blockIdx.x * blockDim.x + threadIdx.x; i < n4; i += stride) {
        float4 v = reinterpret_cast<const float4*>(in)[i];
        ushort4 o;
        o.x = bf16_bits(v.x);
        o.y = bf16_bits(v.y);
        o.z = bf16_bits(v.z);
        o.w = bf16_bits(v.w);
        reinterpret_cast<ushort4*>(out)[i] = o;
    }
}

// ---------------------------------------------------------------- transposes

__global__ __launch_bounds__(256) void transpose_f32_bf16_kernel(
    const float* __restrict__ in, bf16_t* __restrict__ out, long ldin, long ldout) {
    __shared__ float tile[32][33];
    int c0 = blockIdx.x * 32, r0 = blockIdx.y * 32;
    int x = threadIdx.x;
#pragma unroll
    for (int yy = 0; yy < 4; ++yy) {
        int y = threadIdx.y + yy * 8;
        tile[y][x] = in[(long)(r0 + y) * ldin + c0 + x];
    }
    __syncthreads();
#pragma unroll
    for (int yy = 0; yy < 4; ++yy) {
        int y = threadIdx.y + yy * 8;
        out[(long)(c0 + y) * ldout + r0 + x] = __float2bfloat16(tile[x][y]);
    }
}

__global__ __launch_bounds__(256) void transpose_bf16_kernel(
    const bf16_t* __restrict__ in, bf16_t* __restrict__ out,
    long ldin, long ldout, long sIn, long sOut) {
    __shared__ bf16_t tile[32][33];
    in  += (long)blockIdx.z * sIn;
    out += (long)blockIdx.z * sOut;
    int c0 = blockIdx.x * 32, r0 = blockIdx.y * 32;
    int x = threadIdx.x;
#pragma unroll
    for (int yy = 0; yy < 4; ++yy) {
        int y = threadIdx.y + yy * 8;
        tile[y][x] = in[(long)(r0 + y) * ldin + c0 + x];
    }
    __syncthreads();
#pragma unroll
    for (int yy = 0; yy < 4; ++yy) {
        int y = threadIdx.y + yy * 8;
        out[(long)(c0 + y) * ldout + r0 + x] = tile[x][y];
    }
}

// ---------------------------------------------------------------- 256x256 8-wave GEMM, reg-prefetch pipeline
// C[M,N] = scale*(A[M,K] @ Bt[N,K]^T) + bias[N]
// 512 threads = 8 waves (2M x 4N); per-wave 128x64 output; BK=32 per K-tile.
// LDS: 4 rotating buffers x (A[256][32] + B[256][32]) = 128 KiB, XOR-swizzled
// (byte ^= ((row>>1)&3)<<4, measured zero-conflict), inverse-swizzled global src.
// Per tile t (ONE barrier): read ahi(t) [hides under MFMA-lo] | MFMA-lo |
// vmcnt(4) + s_barrier  <-- cross-wave guarantee that tile t+1's staging
// landed (vmcnt is per-wave; fragments are staged cooperatively, so the
// barrier MUST precede the next-tile reads - round-8 race fix) |
// read alo/bf(t+1) + STAGE(t+3) [hide under MFMA-hi] | MFMA-hi.
// Staging lookahead 3 tiles; vmcnt(4) once per tile, never drained.
// Loop unrolled 2 tiles (NT always even) so frag register sets are static.

__global__ __launch_bounds__(512, 2) void gemm256_kernel(
    const bf16_t* __restrict__ A, const bf16_t* __restrict__ Bt,
    void* __restrict__ Cp, const float* __restrict__ bias,
    float scale, int K,
    long lda, long ldb, long ldc,
    long strideA, long strideB, long strideC,
    int mtiles, int causal_skip, int causal_klimit, int c_f32)
{
    __shared__ __align__(16) bf16_t As[4][256 * 32];
    __shared__ __align__(16) bf16_t Bs[4][256 * 32];

    // XCD-aware bijective swizzle (grid.x % 8 == 0 guaranteed by launcher)
    int nwg = gridDim.x;
    int bid = blockIdx.x;
    int swz = (bid & 7) * (nwg >> 3) + (bid >> 3);
    int bm_t = swz % mtiles, bn_t = swz / mtiles;
    if (causal_skip && bn_t > bm_t) return;   // uniform across block
    long bm0 = (long)bm_t * 256, bn0 = (long)bn_t * 256;

    int b = blockIdx.z;
    const char* Ab = (const char*)(A + (long)b * strideA + bm0 * lda);
    const char* Bb = (const char*)(Bt + (long)b * strideB + bn0 * ldb);
    long ldab = lda * 2, ldbb = ldb * 2;

    int tid = threadIdx.x, wave = tid >> 6, lane = tid & 63;
    int wm = wave >> 2, wn = wave & 3;
    int lr = lane & 15, kc = lane >> 4;

    int Kend = K;
    if (causal_klimit) { long kl = bm0 + 256; Kend = (kl < (long)K) ? (int)kl : K; }
    int NT = Kend >> 5;        // K-tiles of 32 (always even, >= 8 here)

    // ---- staging geometry: half-tile = 128 rows x 64B; one gld_lds = 1KB/wave
    int offw = wave * 1024 + lane * 16;     // byte pos within 8KB half
    int rih  = offw >> 6;                   // row in half (0..127)
    long colswz = (long)(((lane & 3) ^ ((rih >> 1) & 3)) << 4);  // inverse-swizzled source slot
    long rowbA0 = (long)rih * ldab, rowbA1 = (long)(rih + 128) * ldab;
    long rowbB0 = (long)rih * ldbb, rowbB1 = (long)(rih + 128) * ldbb;
    int ldsoff = wave * 1024;

    auto STAGE = [&](int t, int buf) {   // 4 gld_lds: A half0/1, B half0/1
        gld_lds16(Ab + rowbA0 + (long)t * 64 + colswz, (char*)As + buf * 16384 + ldsoff);
        gld_lds16(Ab + rowbA1 + (long)t * 64 + colswz, (char*)As + buf * 16384 + 8192 + ldsoff);
        gld_lds16(Bb + rowbB0 + (long)t * 64 + colswz, (char*)Bs + buf * 16384 + ldsoff);
        gld_lds16(Bb + rowbB1 + (long)t * 64 + colswz, (char*)Bs + buf * 16384 + 8192 + ldsoff);
    };

    // ---- fragment read byte-offsets (swizzled), loop-invariant
    int aoff[8], boff[4];
#pragma unroll
    for (int m = 0; m < 8; ++m) {
        int row = wm * 128 + m * 16 + lr;
        aoff[m] = (row * 64 + kc * 16) ^ (((row >> 1) & 3) << 4);
    }
#pragma unroll
    for (int n = 0; n < 4; ++n) {
        int row = wn * 64 + n * 16 + lr;
        boff[n] = (row * 64 + kc * 16) ^ (((row >> 1) & 3) << 4);
    }

    f32x4 acc[8][4];
#pragma unroll
    for (int m = 0; m < 8; ++m)
#pragma unroll
        for (int n = 0; n < 4; ++n) acc[m][n] = (f32x4){0.f, 0.f, 0.f, 0.f};

    // ---- prologue: stage tiles 0,1,2 (12 calls); wait tile0 (8 in flight)
    STAGE(0, 0); STAGE(1, 1); STAGE(2, 2);
    asm volatile("s_waitcnt vmcnt(8)" ::: "memory");
    __builtin_amdgcn_s_barrier();

    bf16x8 alo[4], ahi[4], bfA[4], bfB[4];
    {   // preload tile0 lo-fragments (tile0 landed for all waves)
        const char* A0 = (const char*)As;
        const char* B0 = (const char*)Bs;
#pragma unroll
        for (int m = 0; m < 4; ++m) alo[m] = *(const bf16x8*)(A0 + aoff[m]);
#pragma unroll
        for (int n = 0; n < 4; ++n) bfA[n] = *(const bf16x8*)(B0 + boff[n]);
    }

    int NI = NT >> 1;
    for (int i = 0; i < NI; ++i) {
        int tE = 2 * i, tO = tE + 1;
        const char* AcE = (const char*)As + (tE & 3) * 16384;
        const char* AcO = (const char*)As + (tO & 3) * 16384;
        const char* BcO = (const char*)Bs + (tO & 3) * 16384;
        const char* AcN = (const char*)As + ((tE + 2) & 3) * 16384;  // tile tE+2
        const char* BcN = (const char*)Bs + ((tE + 2) & 3) * 16384;

        // ================= tile tE (uses alo, bfA) =================
#pragma unroll
        for (int m = 0; m < 4; ++m) ahi[m] = *(const bf16x8*)(AcE + aoff[m + 4]);
        __builtin_amdgcn_sched_barrier(0);
        __builtin_amdgcn_s_setprio(1);
#pragma unroll
        for (int m = 0; m < 4; ++m)
#pragma unroll
            for (int n = 0; n < 4; ++n)
                acc[m][n] = __builtin_amdgcn_mfma_f32_16x16x32_bf16(alo[m], bfA[n], acc[m][n], 0, 0, 0);
        __builtin_amdgcn_s_setprio(0);
        asm volatile("s_waitcnt vmcnt(4)" ::: "memory");   // own tile tE+1 loads landed
        __builtin_amdgcn_s_barrier();                      // ALL waves' tile tE+1 landed
#pragma unroll
        for (int m = 0; m < 4; ++m) alo[m] = *(const bf16x8*)(AcO + aoff[m]);
#pragma unroll
        for (int n = 0; n < 4; ++n) bfB[n] = *(const bf16x8*)(BcO + boff[n]);
        { int ts = (tE + 3 < NT) ? tE + 3 : NT - 1; STAGE(ts, (tE + 3) & 3); }
        __builtin_amdgcn_sched_barrier(0);
        __builtin_amdgcn_s_setprio(1);
#pragma unroll
        for (int m = 0; m < 4; ++m)
#pragma unroll
            for (int n = 0; n < 4; ++n)
                acc[m + 4][n] = __builtin_amdgcn_mfma_f32_16x16x32_bf16(ahi[m], bfA[n], acc[m + 4][n], 0, 0, 0);
        __builtin_amdgcn_s_setprio(0);

        // ================= tile tO (uses alo, bfB) =================
#pragma unroll
        for (int m = 0; m < 4; ++m) ahi[m] = *(const bf16x8*)(AcO + aoff[m + 4]);
        __builtin_amdgcn_sched_barrier(0);
        __builtin_amdgcn_s_setprio(1);
#pragma unroll
        for (int m = 0; m < 4; ++m)
#pragma unroll
            for (int n = 0; n < 4; ++n)
                acc[m][n] = __builtin_amdgcn_mfma_f32_16x16x32_bf16(alo[m], bfB[n], acc[m][n], 0, 0, 0);
        __builtin_amdgcn_s_setprio(0);
        asm volatile("s_waitcnt vmcnt(4)" ::: "memory");   // own tile tO+1 loads landed
        __builtin_amdgcn_s_barrier();                      // ALL waves' tile tO+1 landed
#pragma unroll
        for (int m = 0; m < 4; ++m) alo[m] = *(const bf16x8*)(AcN + aoff[m]);   // phantom at last iter (unused)
#pragma unroll
        for (int n = 0; n < 4; ++n) bfA[n] = *(const bf16x8*)(BcN + boff[n]);
        { int ts = (tO + 3 < NT) ? tO + 3 : NT - 1; STAGE(ts, (tO + 3) & 3); }
        __builtin_amdgcn_sched_barrier(0);
        __builtin_amdgcn_s_setprio(1);
#pragma unroll
        for (int m = 0; m < 4; ++m)
#pragma unroll
            for (int n = 0; n < 4; ++n)
                acc[m + 4][n] = __builtin_amdgcn_mfma_f32_16x16x32_bf16(ahi[m], bfB[n], acc[m + 4][n], 0, 0, 0);
        __builtin_amdgcn_s_setprio(0);
    }

    asm volatile("s_waitcnt vmcnt(0)" ::: "memory");

    // ---- epilogue: D[row=(lane>>4)*4+r][col=lane&15] per 16x16 fragment
#pragma unroll
    for (int m = 0; m < 8; ++m) {
        long row = bm0 + wm * 128 + m * 16 + kc * 4;
#pragma unroll
        for (int n = 0; n < 4; ++n) {
            long col = bn0 + wn * 64 + n * 16 + lr;
            float bv = bias ? bias[col] : 0.f;
            if (c_f32) {
                float* Crow = (float*)Cp + (long)b * strideC;
#pragma unroll
                for (int r = 0; r < 4; ++r)
                    Crow[(row + r) * ldc + col] = acc[m][n][r] * scale + bv;
            } else {
                bf16_t* Crow = (bf16_t*)Cp + (long)b * strideC;
#pragma unroll
                for (int r = 0; r < 4; ++r)
                    Crow[(row + r) * ldc + col] = __float2bfloat16(acc[m][n][r] * scale + bv);
            }
        }
    }
}

// ---------------------------------------------------------------- causal softmax (in-place, bf16)

__global__ __launch_bounds__(256) void softmax_causal_kernel(bf16_t* S, int T) {
    int t = blockIdx.x;
    bf16_t* row = S + ((long)blockIdx.y * T + t) * (long)T;
    int tid = threadIdx.x;
    int s0 = tid * 8;

    u16x8 raw = *reinterpret_cast<const u16x8*>(&row[s0]);
    float v[8];
#pragma unroll
    for (int j = 0; j < 8; ++j) v[j] = __uint_as_float(((unsigned)raw[j]) << 16);

    float m = -1e30f;
#pragma unroll
    for (int j = 0; j < 8; ++j)
        if (s0 + j <= t) m = fmaxf(m, v[j]);

    __shared__ float red[8];
#pragma unroll
    for (int o = 32; o; o >>= 1) m = fmaxf(m, __shfl_xor(m, o, 64));
    if ((tid & 63) == 0) red[tid >> 6] = m;
    __syncthreads();
    m = fmaxf(fmaxf(red[0], red[1]), fmaxf(red[2], red[3]));
    __syncthreads();

    float e[8];
    float sum = 0.f;
#pragma unroll
    for (int j = 0; j < 8; ++j) {
        e[j] = (s0 + j <= t) ? __expf(v[j] - m) : 0.f;
        sum += e[j];
    }
#pragma unroll
    for (int o = 32; o; o >>= 1) sum += __shfl_xor(sum, o, 64);
    if ((tid & 63) == 0) red[tid >> 6] = sum;
    __syncthreads();
    sum = red[0] + red[1] + red[2] + red[3];
    float inv = 1.f / sum;

    u16x8 outp;
#pragma unroll
    for (int j = 0; j < 8; ++j) outp[j] = bf16_bits(e[j] * inv);
    *reinterpret_cast<u16x8*>(&row[s0]) = outp;
}

// ---------------------------------------------------------------- launch

extern "C" void kernel_launch(void* const* d_in, const int* in_sizes, int n_in,
                              void* d_out, int out_size, void* d_ws, size_t ws_size,
                              hipStream_t stream) {
    const int B = 8, T = 2048, C = 1024;
    const int M = B * T;            // 16384
    const int N3 = 3 * C;           // 3072

    const float* x      = (const float*)d_in[0];
    const float* w_attn = (const float*)d_in[1];
    const float* b_attn = (const float*)d_in[2];
    const float* w_proj = (const float*)d_in[3];
    const float* b_proj = (const float*)d_in[4];
    float* out = (float*)d_out;     // reference output dtype is fp32

    char* ws = (char*)d_ws;

    // ---- adaptive workspace tiering ----
    const size_t BASE_FULL = 142606336ull;   // weights + qkv + xb/O
    const size_t PER_B     = 12582912ull;    // vT_b + S_b
    long NB = 0;
    if (ws_size >= BASE_FULL + PER_B) {
        NB = (long)((ws_size - BASE_FULL) / PER_B);
        if (NB > 8) NB = 8;
    }

    if (NB >= 1) {
        // ---------------- chunked path
        bf16_t* waT = (bf16_t*)(ws);                    // [3C, C]   6.3 MB
        bf16_t* wpT = (bf16_t*)(ws + 6291456);          // [C, C]    2.1 MB
        bf16_t* qkv = (bf16_t*)(ws + 8388608);          // [M, 3C] 100.7 MB
        bf16_t* xbO = (bf16_t*)(ws + 109051904);        // [M, C]   33.5 MB (xb, then O)
        bf16_t* vT  = (bf16_t*)(ws + 142606336);        // [NB, C, T]
        bf16_t* S   = (bf16_t*)(ws + 142606336 + (size_t)NB * 4194304); // [NB, T, T]

        cvt_f32_bf16_kernel<<<2048, 256, 0, stream>>>(x, xbO, (long)M * C / 4);

        transpose_f32_bf16_kernel<<<dim3(N3 / 32, C / 32, 1), dim3(32, 8), 0, stream>>>(
            w_attn, waT, N3, C);
        transpose_f32_bf16_kernel<<<dim3(C / 32, C / 32, 1), dim3(32, 8), 0, stream>>>(
            w_proj, wpT, C, C);

        // qkv = xb @ w_attn + b_attn
        gemm256_kernel<<<dim3((M / 256) * (N3 / 256), 1, 1), 512, 0, stream>>>(
            xbO, waT, qkv, b_attn, 1.0f, C,
            C, C, N3, 0, 0, 0, M / 256, 0, 0, 0);

        for (long b0 = 0; b0 < B; b0 += NB) {
            long nb = (B - b0 < NB) ? (B - b0) : NB;
            const bf16_t* qkv_c = qkv + b0 * (long)T * N3;
            bf16_t* O_c = xbO + b0 * (long)T * C;

            transpose_bf16_kernel<<<dim3(C / 32, T / 32, nb), dim3(32, 8), 0, stream>>>(
                qkv_c + 2 * C, vT, N3, T, (long)T * N3, (long)C * T);

            // S = (Q K^T)/sqrt(C), causal block-skip
            gemm256_kernel<<<dim3((T / 256) * (T / 256), 1, nb), 512, 0, stream>>>(
                qkv_c, qkv_c + C, S, nullptr, 0.03125f, C,
                N3, N3, T, (long)T * N3, (long)T * N3, (long)T * T, T / 256, 1, 0, 0);

            softmax_causal_kernel<<<dim3(T, nb), 256, 0, stream>>>(S, T);

            // O = P @ V, causal K-limit
            gemm256_kernel<<<dim3((T / 256) * (C / 256), 1, nb), 512, 0, stream>>>(
                S, vT, O_c, nullptr, 1.0f, T,
                T, T, C, (long)T * T, (long)C * T, (long)T * C, T / 256, 0, 1, 0);
        }

        // out = O @ w_proj + b_proj   (fp32 store into d_out)
        gemm256_kernel<<<dim3((M / 256) * (C / 256), 1, 1), 512, 0, stream>>>(
            xbO, wpT, out, b_proj, 1.0f, C,
            C, C, C, 0, 0, 0, M / 256, 0, 0, 1);
    } else {
        // ---------------- per-batch fallback (36 MB total)
        bf16_t* waT  = (bf16_t*)(ws);                   // [3C, C]   6.3 MB
        bf16_t* wpT  = (bf16_t*)(ws + 6291456);         // [C, C]    2.1 MB
        bf16_t* xbO  = (bf16_t*)(ws + 8388608);         // [T, C]    4.2 MB
        bf16_t* qkvb = (bf16_t*)(ws + 12582912);        // [T, 3C]  12.6 MB
        bf16_t* vTb  = (bf16_t*)(ws + 25165824);        // [C, T]    4.2 MB
        bf16_t* Sb   = (bf16_t*)(ws + 29360128);        // [T, T]    8.4 MB

        transpose_f32_bf16_kernel<<<dim3(N3 / 32, C / 32, 1), dim3(32, 8), 0, stream>>>(
            w_attn, waT, N3, C);
        transpose_f32_bf16_kernel<<<dim3(C / 32, C / 32, 1), dim3(32, 8), 0, stream>>>(
            w_proj, wpT, C, C);

        for (int b = 0; b < B; ++b) {
            const float* x_b = x + (long)b * T * C;
            float* out_b = out + (long)b * T * C;

            cvt_f32_bf16_kernel<<<1024, 256, 0, stream>>>(x_b, xbO, (long)T * C / 4);

            gemm256_kernel<<<dim3((T / 256) * (N3 / 256), 1, 1), 512, 0, stream>>>(
                xbO, waT, qkvb, b_attn, 1.0f, C,
                C, C, N3, 0, 0, 0, T / 256, 0, 0, 0);

            transpose_bf16_kernel<<<dim3(C / 32, T / 32, 1), dim3(32, 8), 0, stream>>>(
                qkvb + 2 * C, vTb, N3, T, 0, 0);

            gemm256_kernel<<<dim3((T / 256) * (T / 256), 1, 1), 512, 0, stream>>>(
                qkvb, qkvb + C, Sb, nullptr, 0.03125f, C,
                N3, N3, T, 0, 0, 0, T / 256, 1, 0, 0);

            softmax_causal_kernel<<<dim3(T, 1), 256, 0, stream>>>(Sb, T);

            gemm256_kernel<<<dim3((T / 256) * (C / 256), 1, 1), 512, 0, stream>>>(
                Sb, vTb, xbO, nullptr, 1.0f, T,
                T, T, C, 0, 0, 0, T / 256, 0, 1, 0);

            gemm256_kernel<<<dim3((T / 256) * (C / 256), 1, 1), 512, 0, stream>>>(
                xbO, wpT, out_b, b_proj, 1.0f, C,
                C, C, C, 0, 0, 0, T / 256, 0, 0, 1);
        }
    }
}

// Round 10
// 361.791 us; speedup vs baseline: 1.1074x; 1.1074x over previous
//
#include <hip/hip_runtime.h>
#include <hip/hip_bf16.h>

typedef __hip_bfloat16 bf16_t;
typedef __attribute__((ext_vector_type(8))) __bf16 bf16x8;
typedef __attribute__((ext_vector_type(4))) float f32x4;
typedef __attribute__((ext_vector_type(8))) unsigned short u16x8;

// ---------------------------------------------------------------- helpers

__device__ __forceinline__ void gld_lds16(const void* g, void* l) {
    // async global->LDS, 16B per lane. LDS dest is wave-uniform base + lane*16.
    __builtin_amdgcn_global_load_lds(
        (const __attribute__((address_space(1))) unsigned int*)g,
        (__attribute__((address_space(3))) unsigned int*)l,
        16, 0, 0);
}

__device__ __forceinline__ unsigned short bf16_bits(float x) {
    bf16_t b = __float2bfloat16(x);
    return *reinterpret_cast<unsigned short*>(&b);
}

// ---------------------------------------------------------------- convert x -> bf16

__global__ __launch_bounds__(256) void cvt_f32_bf16_kernel(
    const float* __restrict__ in, bf16_t* __restrict__ out, long n4) {
    long stride = (long)gridDim.x * blockDim.x;
    for (long i = (long)blockIdx.x * blockDim.x + threadIdx.x; i < n4; i += stride) {
        float4 v = reinterpret_cast<const float4*>(in)[i];
        ushort4 o;
        o.x = bf16_bits(v.x);
        o.y = bf16_bits(v.y);
        o.z = bf16_bits(v.z);
        o.w = bf16_bits(v.w);
        reinterpret_cast<ushort4*>(out)[i] = o;
    }
}

// ---------------------------------------------------------------- transposes

__global__ __launch_bounds__(256) void transpose_f32_bf16_kernel(
    const float* __restrict__ in, bf16_t* __restrict__ out, long ldin, long ldout) {
    __shared__ float tile[32][33];
    int c0 = blockIdx.x * 32, r0 = blockIdx.y * 32;
    int x = threadIdx.x;
#pragma unroll
    for (int yy = 0; yy < 4; ++yy) {
        int y = threadIdx.y + yy * 8;
        tile[y][x] = in[(long)(r0 + y) * ldin + c0 + x];
    }
    __syncthreads();
#pragma unroll
    for (int yy = 0; yy < 4; ++yy) {
        int y = threadIdx.y + yy * 8;
        out[(long)(c0 + y) * ldout + r0 + x] = __float2bfloat16(tile[x][y]);
    }
}

__global__ __launch_bounds__(256) void transpose_bf16_kernel(
    const bf16_t* __restrict__ in, bf16_t* __restrict__ out,
    long ldin, long ldout, long sIn, long sOut) {
    __shared__ bf16_t tile[32][33];
    in  += (long)blockIdx.z * sIn;
    out += (long)blockIdx.z * sOut;
    int c0 = blockIdx.x * 32, r0 = blockIdx.y * 32;
    int x = threadIdx.x;
#pragma unroll
    for (int yy = 0; yy < 4; ++yy) {
        int y = threadIdx.y + yy * 8;
        tile[y][x] = in[(long)(r0 + y) * ldin + c0 + x];
    }
    __syncthreads();
#pragma unroll
    for (int yy = 0; yy < 4; ++yy) {
        int y = threadIdx.y + yy * 8;
        out[(long)(c0 + y) * ldout + r0 + x] = tile[x][y];
    }
}

// ---------------------------------------------------------------- 256x256 8-wave GEMM, 1 barrier / K-tile
// (round-7 inner loop, best measured; new: panel-resident XCD mapping)
// swz_mode=1 (uniform-K GEMMs): xcd = bid&7 owns a contiguous group of
//   mtiles/8 A-panels; bm varies FAST within the XCD (A group ~4MB stays
//   L2-resident), bn slow (B-panels stream). Fixes per-XCD A-thrash
//   (round-9 qkv FETCH=202MB ~= 6x A).
// swz_mode=0 (causal QK^T / K-limited PV): old generic swizzle - panel
//   mapping would give XCD k work ~ (k+1) -> 1.8x makespan imbalance.

__global__ __launch_bounds__(512, 2) void gemm256_kernel(
    const bf16_t* __restrict__ A, const bf16_t* __restrict__ Bt,
    void* __restrict__ Cp, const float* __restrict__ bias,
    float scale, int K,
    long lda, long ldb, long ldc,
    long strideA, long strideB, long strideC,
    int mtiles, int causal_skip, int causal_klimit, int c_f32, int swz_mode)
{
    __shared__ __align__(16) bf16_t As[3][256 * 32];
    __shared__ __align__(16) bf16_t Bs[3][256 * 32];

    int nwg = gridDim.x;
    int bid = blockIdx.x;
    int bm_t, bn_t;
    if (swz_mode == 1 && (mtiles & 7) == 0 && (nwg & 7) == 0) {
        int xcd = bid & 7;
        int l   = bid >> 3;          // local index within this XCD's chunk
        int mpx = mtiles >> 3;       // A-panels owned per XCD
        bm_t = xcd * mpx + (l % mpx);   // bm fast: A group L2-resident
        bn_t = l / mpx;                 // bn slow: B-panels stream 1-at-a-time
    } else {
        int swz = (bid & 7) * (nwg >> 3) + (bid >> 3);
        bm_t = swz % mtiles; bn_t = swz / mtiles;
    }
    if (causal_skip && bn_t > bm_t) return;   // uniform across block
    long bm0 = (long)bm_t * 256, bn0 = (long)bn_t * 256;

    int b = blockIdx.z;
    const char* Ab = (const char*)(A + (long)b * strideA + bm0 * lda);
    const char* Bb = (const char*)(Bt + (long)b * strideB + bn0 * ldb);
    long ldab = lda * 2, ldbb = ldb * 2;

    int tid = threadIdx.x, wave = tid >> 6, lane = tid & 63;
    int wm = wave >> 2, wn = wave & 3;
    int lr = lane & 15, kc = lane >> 4;

    int Kend = K;
    if (causal_klimit) { long kl = bm0 + 256; Kend = (kl < (long)K) ? (int)kl : K; }
    int NT = Kend >> 5;        // K-tiles of 32 (always >= 8 here)

    // ---- staging geometry: half-tile = 128 rows x 64B; one gld_lds = 1KB/wave
    int offw = wave * 1024 + lane * 16;     // byte pos within 8KB half
    int rih  = offw >> 6;                   // row in half (0..127)
    long colswz = (long)(((lane & 3) ^ ((rih >> 1) & 3)) << 4);  // inverse-swizzled source slot
    long rowbA0 = (long)rih * ldab, rowbA1 = (long)(rih + 128) * ldab;
    long rowbB0 = (long)rih * ldbb, rowbB1 = (long)(rih + 128) * ldbb;
    int ldsoff = wave * 1024;

    auto STA = [&](int t, int h, int buf) {
        gld_lds16(Ab + (h ? rowbA1 : rowbA0) + (long)t * 64 + colswz,
                  (char*)As + buf * 16384 + h * 8192 + ldsoff);
    };
    auto STB = [&](int t, int h, int buf) {
        gld_lds16(Bb + (h ? rowbB1 : rowbB0) + (long)t * 64 + colswz,
                  (char*)Bs + buf * 16384 + h * 8192 + ldsoff);
    };

    // ---- fragment read byte-offsets (swizzled), loop-invariant
    int aoff[8], boff[4];
#pragma unroll
    for (int m = 0; m < 8; ++m) {
        int row = wm * 128 + m * 16 + lr;
        aoff[m] = (row * 64 + kc * 16) ^ (((row >> 1) & 3) << 4);
    }
#pragma unroll
    for (int n = 0; n < 4; ++n) {
        int row = wn * 64 + n * 16 + lr;
        boff[n] = (row * 64 + kc * 16) ^ (((row >> 1) & 3) << 4);
    }

    f32x4 acc[8][4];
#pragma unroll
    for (int m = 0; m < 8; ++m)
#pragma unroll
        for (int n = 0; n < 4; ++n) acc[m][n] = (f32x4){0.f, 0.f, 0.f, 0.f};

    // ---- prologue: tiles 0 and 1 fully staged; wait tile0 (tile1's 4 in flight)
    STA(0, 0, 0); STA(0, 1, 0); STB(0, 0, 0); STB(0, 1, 0);
    STA(1, 0, 1); STA(1, 1, 1); STB(1, 0, 1); STB(1, 1, 1);
    asm volatile("s_waitcnt vmcnt(4)" ::: "memory");
    __builtin_amdgcn_s_barrier();

    int cur = 0;

    for (int t = 0; t < NT; ++t) {
        int b2 = cur + 2; if (b2 >= 3) b2 -= 3;       // buf for tile t+2 (holds dead t-1)
        int t2 = (t + 2 < NT) ? (t + 2) : NT - 1;     // tail: redundant re-stage (never read)
        const char* Ac = (const char*)As + cur * 16384;
        const char* Bc = (const char*)Bs + cur * 16384;

        bf16x8 alo[4], ahi[4], bfr[4];
#pragma unroll
        for (int m = 0; m < 4; ++m) alo[m] = *(const bf16x8*)(Ac + aoff[m]);
#pragma unroll
        for (int n = 0; n < 4; ++n) bfr[n] = *(const bf16x8*)(Bc + boff[n]);
#pragma unroll
        for (int m = 0; m < 4; ++m) ahi[m] = *(const bf16x8*)(Ac + aoff[m + 4]);

        STA(t2, 0, b2); STA(t2, 1, b2);
        STB(t2, 0, b2); STB(t2, 1, b2);
        __builtin_amdgcn_sched_barrier(0);   // keep reads+stages above the MFMA cluster

        __builtin_amdgcn_s_setprio(1);
#pragma unroll
        for (int m = 0; m < 4; ++m)
#pragma unroll
            for (int n = 0; n < 4; ++n)
                acc[m][n] = __builtin_amdgcn_mfma_f32_16x16x32_bf16(alo[m], bfr[n], acc[m][n], 0, 0, 0);
#pragma unroll
        for (int m = 0; m < 4; ++m)
#pragma unroll
            for (int n = 0; n < 4; ++n)
                acc[m + 4][n] = __builtin_amdgcn_mfma_f32_16x16x32_bf16(ahi[m], bfr[n], acc[m + 4][n], 0, 0, 0);
        __builtin_amdgcn_s_setprio(0);

        asm volatile("s_waitcnt vmcnt(4)" ::: "memory");   // t+1 landed; t+2 stays in flight
        __builtin_amdgcn_s_barrier();

        cur += 1; if (cur >= 3) cur -= 3;
    }

    asm volatile("s_waitcnt vmcnt(0)" ::: "memory");

    // ---- epilogue: D[row=(lane>>4)*4+r][col=lane&15] per 16x16 fragment
#pragma unroll
    for (int m = 0; m < 8; ++m) {
        long row = bm0 + wm * 128 + m * 16 + kc * 4;
#pragma unroll
        for (int n = 0; n < 4; ++n) {
            long col = bn0 + wn * 64 + n * 16 + lr;
            float bv = bias ? bias[col] : 0.f;
            if (c_f32) {
                float* Crow = (float*)Cp + (long)b * strideC;
#pragma unroll
                for (int r = 0; r < 4; ++r)
                    Crow[(row + r) * ldc + col] = acc[m][n][r] * scale + bv;
            } else {
                bf16_t* Crow = (bf16_t*)Cp + (long)b * strideC;
#pragma unroll
                for (int r = 0; r < 4; ++r)
                    Crow[(row + r) * ldc + col] = __float2bfloat16(acc[m][n][r] * scale + bv);
            }
        }
    }
}

// ---------------------------------------------------------------- causal softmax (in-place, bf16)
// Traffic-trimmed: skip loads where s0 > t (all-masked vectors), skip stores
// at cols >= klim = ((t>>8)+1)<<8 (PV's causal K-limit means they are never
// read). Cols in [t+1, klim) ARE read by PV and get explicit zeros.

__global__ __launch_bounds__(256) void softmax_causal_kernel(bf16_t* S, int T) {
    int t = blockIdx.x;
    bf16_t* row = S + ((long)blockIdx.y * T + t) * (long)T;
    int tid = threadIdx.x;
    int s0 = tid * 8;
    int klim = ((t >> 8) + 1) << 8;

    u16x8 raw = {};
    if (s0 <= t) raw = *reinterpret_cast<const u16x8*>(&row[s0]);
    float v[8];
#pragma unroll
    for (int j = 0; j < 8; ++j) v[j] = __uint_as_float(((unsigned)raw[j]) << 16);

    float m = -1e30f;
#pragma unroll
    for (int j = 0; j < 8; ++j)
        if (s0 + j <= t) m = fmaxf(m, v[j]);

    __shared__ float red[8];
#pragma unroll
    for (int o = 32; o; o >>= 1) m = fmaxf(m, __shfl_xor(m, o, 64));
    if ((tid & 63) == 0) red[tid >> 6] = m;
    __syncthreads();
    m = fmaxf(fmaxf(red[0], red[1]), fmaxf(red[2], red[3]));
    __syncthreads();

    float e[8];
    float sum = 0.f;
#pragma unroll
    for (int j = 0; j < 8; ++j) {
        e[j] = (s0 + j <= t) ? __expf(v[j] - m) : 0.f;
        sum += e[j];
    }
#pragma unroll
    for (int o = 32; o; o >>= 1) sum += __shfl_xor(sum, o, 64);
    if ((tid & 63) == 0) red[tid >> 6] = sum;
    __syncthreads();
    sum = red[0] + red[1] + red[2] + red[3];
    float inv = 1.f / sum;

    if (s0 < klim) {
        u16x8 outp;
#pragma unroll
        for (int j = 0; j < 8; ++j) outp[j] = bf16_bits(e[j] * inv);
        *reinterpret_cast<u16x8*>(&row[s0]) = outp;
    }
}

// ---------------------------------------------------------------- launch

extern "C" void kernel_launch(void* const* d_in, const int* in_sizes, int n_in,
                              void* d_out, int out_size, void* d_ws, size_t ws_size,
                              hipStream_t stream) {
    const int B = 8, T = 2048, C = 1024;
    const int M = B * T;            // 16384
    const int N3 = 3 * C;           // 3072

    const float* x      = (const float*)d_in[0];
    const float* w_attn = (const float*)d_in[1];
    const float* b_attn = (const float*)d_in[2];
    const float* w_proj = (const float*)d_in[3];
    const float* b_proj = (const float*)d_in[4];
    float* out = (float*)d_out;     // reference output dtype is fp32

    char* ws = (char*)d_ws;

    // ---- adaptive workspace tiering ----
    const size_t BASE_FULL = 142606336ull;   // weights + qkv + xb/O
    const size_t PER_B     = 12582912ull;    // vT_b + S_b
    long NB = 0;
    if (ws_size >= BASE_FULL + PER_B) {
        NB = (long)((ws_size - BASE_FULL) / PER_B);
        if (NB > 8) NB = 8;
    }

    if (NB >= 1) {
        // ---------------- chunked path
        bf16_t* waT = (bf16_t*)(ws);                    // [3C, C]   6.3 MB
        bf16_t* wpT = (bf16_t*)(ws + 6291456);          // [C, C]    2.1 MB
        bf16_t* qkv = (bf16_t*)(ws + 8388608);          // [M, 3C] 100.7 MB
        bf16_t* xbO = (bf16_t*)(ws + 109051904);        // [M, C]   33.5 MB (xb, then O)
        bf16_t* vT  = (bf16_t*)(ws + 142606336);        // [NB, C, T]
        bf16_t* S   = (bf16_t*)(ws + 142606336 + (size_t)NB * 4194304); // [NB, T, T]

        cvt_f32_bf16_kernel<<<2048, 256, 0, stream>>>(x, xbO, (long)M * C / 4);

        transpose_f32_bf16_kernel<<<dim3(N3 / 32, C / 32, 1), dim3(32, 8), 0, stream>>>(
            w_attn, waT, N3, C);
        transpose_f32_bf16_kernel<<<dim3(C / 32, C / 32, 1), dim3(32, 8), 0, stream>>>(
            w_proj, wpT, C, C);

        // qkv = xb @ w_attn + b_attn   (panel-resident swizzle)
        gemm256_kernel<<<dim3((M / 256) * (N3 / 256), 1, 1), 512, 0, stream>>>(
            xbO, waT, qkv, b_attn, 1.0f, C,
            C, C, N3, 0, 0, 0, M / 256, 0, 0, 0, 1);

        for (long b0 = 0; b0 < B; b0 += NB) {
            long nb = (B - b0 < NB) ? (B - b0) : NB;
            const bf16_t* qkv_c = qkv + b0 * (long)T * N3;
            bf16_t* O_c = xbO + b0 * (long)T * C;

            transpose_bf16_kernel<<<dim3(C / 32, T / 32, nb), dim3(32, 8), 0, stream>>>(
                qkv_c + 2 * C, vT, N3, T, (long)T * N3, (long)C * T);

            // S = (Q K^T)/sqrt(C), causal block-skip (balanced old swizzle)
            gemm256_kernel<<<dim3((T / 256) * (T / 256), 1, nb), 512, 0, stream>>>(
                qkv_c, qkv_c + C, S, nullptr, 0.03125f, C,
                N3, N3, T, (long)T * N3, (long)T * N3, (long)T * T, T / 256, 1, 0, 0, 0);

            softmax_causal_kernel<<<dim3(T, nb), 256, 0, stream>>>(S, T);

            // O = P @ V, causal K-limit (balanced old swizzle)
            gemm256_kernel<<<dim3((T / 256) * (C / 256), 1, nb), 512, 0, stream>>>(
                S, vT, O_c, nullptr, 1.0f, T,
                T, T, C, (long)T * T, (long)C * T, (long)T * C, T / 256, 0, 1, 0, 0);
        }

        // out = O @ w_proj + b_proj   (fp32 store, panel-resident swizzle)
        gemm256_kernel<<<dim3((M / 256) * (C / 256), 1, 1), 512, 0, stream>>>(
            xbO, wpT, out, b_proj, 1.0f, C,
            C, C, C, 0, 0, 0, M / 256, 0, 0, 1, 1);
    } else {
        // ---------------- per-batch fallback (36 MB total)
        bf16_t* waT  = (bf16_t*)(ws);                   // [3C, C]   6.3 MB
        bf16_t* wpT  = (bf16_t*)(ws + 6291456);         // [C, C]    2.1 MB
        bf16_t* xbO  = (bf16_t*)(ws + 8388608);         // [T, C]    4.2 MB
        bf16_t* qkvb = (bf16_t*)(ws + 12582912);        // [T, 3C]  12.6 MB
        bf16_t* vTb  = (bf16_t*)(ws + 25165824);        // [C, T]    4.2 MB
        bf16_t* Sb   = (bf16_t*)(ws + 29360128);        // [T, T]    8.4 MB

        transpose_f32_bf16_kernel<<<dim3(N3 / 32, C / 32, 1), dim3(32, 8), 0, stream>>>(
            w_attn, waT, N3, C);
        transpose_f32_bf16_kernel<<<dim3(C / 32, C / 32, 1), dim3(32, 8), 0, stream>>>(
            w_proj, wpT, C, C);

        for (int b = 0; b < B; ++b) {
            const float* x_b = x + (long)b * T * C;
            float* out_b = out + (long)b * T * C;

            cvt_f32_bf16_kernel<<<1024, 256, 0, stream>>>(x_b, xbO, (long)T * C / 4);

            gemm256_kernel<<<dim3((T / 256) * (N3 / 256), 1, 1), 512, 0, stream>>>(
                xbO, waT, qkvb, b_attn, 1.0f, C,
                C, C, N3, 0, 0, 0, T / 256, 0, 0, 0, 1);

            transpose_bf16_kernel<<<dim3(C / 32, T / 32, 1), dim3(32, 8), 0, stream>>>(
                qkvb + 2 * C, vTb, N3, T, 0, 0);

            gemm256_kernel<<<dim3((T / 256) * (T / 256), 1, 1), 512, 0, stream>>>(
                qkvb, qkvb + C, Sb, nullptr, 0.03125f, C,
                N3, N3, T, 0, 0, 0, T / 256, 1, 0, 0, 0);

            softmax_causal_kernel<<<dim3(T, 1), 256, 0, stream>>>(Sb, T);

            gemm256_kernel<<<dim3((T / 256) * (C / 256), 1, 1), 512, 0, stream>>>(
                Sb, vTb, xbO, nullptr, 1.0f, T,
                T, T, C, 0, 0, 0, T / 256, 0, 1, 0, 0);

            gemm256_kernel<<<dim3((T / 256) * (C / 256), 1, 1), 512, 0, stream>>>(
                xbO, wpT, out_b, b_proj, 1.0f, C,
                C, C, C, 0, 0, 0, T / 256, 0, 0, 1, 1);
        }
    }
}